// Round 5
// baseline (103.165 us; speedup 1.0000x reference)
//
#include <hip/hip_runtime.h>
#include <math.h>

#define NH 32     // total modes (N/2)
#define NHALF 16  // modes per thread (lane-split)

typedef float v2f __attribute__((ext_vector_type(2)));

// Reduce x mod 2*pi to [-pi, pi] with 2-term float Cody-Waite.
// PI2_HI = 6.28125 (7-bit mantissa) -> k*PI2_HI exact for k < 2^16.
// Total error ~3e-7 rad for |x| <= ~2.2e4.
__device__ __forceinline__ float reduce2pi(float x) {
    const float INV2PI = 0.15915494309189535f;
    const float PI2_HI = 6.28125f;
    const float PI2_LO = 1.9353071795864769e-3f;
    float k = rintf(x * INV2PI);
    float r = fmaf(-k, PI2_HI, x);
    r = fmaf(-k, PI2_LO, r);
    return r;
}

// One block per h, 256 threads (4 waves), all 1024 blocks resident (4/CU).
// Lane-split: lanes 0-31 handle modes 0-15, lanes 32-63 modes 16-31.
// Each thread carries TWO l-positions (l0+j*128 and L/2+l0+j*128) sharing the
// step multiplier w = exp(dtA*128). w is NOT kept in registers: it is
// re-read from LDS each step (volatile, to defeat LICM) so persistent state
// is only y1[16]+y2[16] = 64 VGPRs -> fits the 128-reg budget of
// launch_bounds(256,4) with no spill (R4's failure mode).
__global__ __launch_bounds__(256, 4) void s4d_kernel(
    const float* __restrict__ log_dt,
    const float* __restrict__ Cv,          // (H, 32, 2)
    const float* __restrict__ log_A_real,  // (H, 32)
    const float* __restrict__ A_imag,      // (H, 32)
    float* __restrict__ Kout,              // (H, L)
    int L)
{
    const int h   = blockIdx.x;
    const int tid = threadIdx.x;
    const int Lh  = L >> 1;                // 2048 = 2^11 (exact fp32 scaling)

    __shared__ float s_ce[NH][2];  // C_eff (x2 folded)
    __shared__ float s_w [NH][2];  // w = exp(dtA*128)
    __shared__ float s_B [NH][2];  // B = exp(dtA*L/2)
    __shared__ float s_da[NH][2];  // (dar, dai)

    // ---- Phase A: per-(h,n) uniforms; 32 threads; HW trans only ----
    if (tid < NH) {
        const int n = tid;
        const float dt  = __expf(log_dt[h]);
        const float Ar  = -__expf(log_A_real[h * NH + n]);
        const float Ai  = A_imag[h * NH + n];
        const float dar = Ar * dt;
        const float dai = Ai * dt;

        // C_eff = 2 * C * (exp(dtA) - 1) / A
        float er = __expf(dar);
        float sn, cs;
        __sincosf(dai, &sn, &cs);          // |dai| <= ~9.8
        float edr = fmaf(er, cs, -1.0f);
        float edi = er * sn;
        float inv = 1.0f / fmaf(Ar, Ar, Ai * Ai);
        float fr  = (edr * Ar + edi * Ai) * inv;
        float fi  = (edi * Ar - edr * Ai) * inv;
        float cr  = Cv[(h * NH + n) * 2 + 0];
        float ci  = Cv[(h * NH + n) * 2 + 1];
        s_ce[n][0] = 2.0f * (cr * fr - ci * fi);
        s_ce[n][1] = 2.0f * (cr * fi + ci * fr);

        // w = exp(dtA*128); dai*128 exact (power of 2)
        float ew  = __expf(dar * 128.0f);
        float thw = reduce2pi(dai * 128.0f);
        float sw, cw;
        __sincosf(thw, &sw, &cw);
        s_w[n][0] = ew * cw;
        s_w[n][1] = ew * sw;

        // B = exp(dtA*Lh); dai*Lh exact (power of 2); may underflow (mode dead)
        float Bf  = (float)Lh;
        float eB  = __expf(dar * Bf);
        float thB = reduce2pi(dai * Bf);
        float sB, cB;
        __sincosf(thB, &sB, &cB);
        s_B[n][0] = eB * cB;
        s_B[n][1] = eB * sB;

        s_da[n][0] = dar;
        s_da[n][1] = dai;
    }
    __syncthreads();

    // ---- Phase B: per-thread state init ----
    const int lane = tid & 63;
    const int half = lane >> 5;                       // 0: modes 0-15, 1: 16-31
    const int l0   = (tid >> 6) * 32 + (lane & 31);   // 0..127
    const float l0f = (float)l0;

    v2f y1[NHALF], y2[NHALF];
    #pragma unroll
    for (int m = 0; m < NHALF; ++m) {
        const int n = half * NHALF + m;
        float dar = s_da[n][0], dai = s_da[n][1];
        float e0 = __expf(dar * l0f);
        float sn, cs;
        __sincosf(dai * l0f, &sn, &cs);               // |ang| <= ~1240 rad
        float zr = e0 * cs, zi = e0 * sn;
        float cr = s_ce[n][0], ci = s_ce[n][1];
        float ar = cr * zr - ci * zi;
        float ai = cr * zi + ci * zr;
        y1[m][0] = ar;
        y1[m][1] = ai;
        // y2 = y1 * B  (seed the second l-position, spaced Lh)
        float Br = s_B[n][0], Bi = s_B[n][1];
        y2[m][0] = ar * Br - ai * Bi;
        y2[m][1] = ar * Bi + ai * Br;
    }

    // Per-thread LDS base for this half's step multipliers.
    const v2f* wp = (const v2f*)&s_w[half * NHALF][0];

    // ---- Main loop: 16 steps; each step produces 256 outputs per block ----
    float* outp = Kout + (size_t)h * (size_t)L + (half ? Lh : 0) + l0;
    const int steps = L >> 8;                         // L/256 = 16
    #pragma unroll 2
    for (int j = 0; j < steps; ++j) {
        v2f a1a = {0.f, 0.f}, a1b = {0.f, 0.f};
        v2f a2a = {0.f, 0.f}, a2b = {0.f, 0.f};
        #pragma unroll
        for (int m = 0; m < NHALF; m += 2) {
            // volatile: keep these as per-step ds_read_b64 (no LICM -> no
            // 32 extra persistent VGPRs; that was R4's spill collapse).
            v2f w0 = ((volatile const v2f*)wp)[m];
            v2f w1 = ((volatile const v2f*)wp)[m + 1];
            a1a += y1[m];  a1b += y1[m + 1];
            a2a += y2[m];  a2b += y2[m + 1];
            v2f t;
            // complex y *= w in 2 VOP3P ops:
            // t = (yr*wr, yr*wi); y' = (-yi*wi + t.lo, yi*wr + t.hi)
            asm("v_pk_mul_f32 %0, %1, %2 op_sel:[0,0] op_sel_hi:[0,1]"
                : "=v"(t) : "v"(y1[m]), "v"(w0));
            asm("v_pk_fma_f32 %0, %1, %2, %3 op_sel:[1,1,0] op_sel_hi:[1,0,1] neg_lo:[0,1,0]"
                : "=v"(y1[m]) : "v"(y1[m]), "v"(w0), "v"(t));
            asm("v_pk_mul_f32 %0, %1, %2 op_sel:[0,0] op_sel_hi:[0,1]"
                : "=v"(t) : "v"(y2[m]), "v"(w0));
            asm("v_pk_fma_f32 %0, %1, %2, %3 op_sel:[1,1,0] op_sel_hi:[1,0,1] neg_lo:[0,1,0]"
                : "=v"(y2[m]) : "v"(y2[m]), "v"(w0), "v"(t));
            asm("v_pk_mul_f32 %0, %1, %2 op_sel:[0,0] op_sel_hi:[0,1]"
                : "=v"(t) : "v"(y1[m + 1]), "v"(w1));
            asm("v_pk_fma_f32 %0, %1, %2, %3 op_sel:[1,1,0] op_sel_hi:[1,0,1] neg_lo:[0,1,0]"
                : "=v"(y1[m + 1]) : "v"(y1[m + 1]), "v"(w1), "v"(t));
            asm("v_pk_mul_f32 %0, %1, %2 op_sel:[0,0] op_sel_hi:[0,1]"
                : "=v"(t) : "v"(y2[m + 1]), "v"(w1));
            asm("v_pk_fma_f32 %0, %1, %2, %3 op_sel:[1,1,0] op_sel_hi:[1,0,1] neg_lo:[0,1,0]"
                : "=v"(y2[m + 1]) : "v"(y2[m + 1]), "v"(w1), "v"(t));
        }
        float acc1 = a1a[0] + a1b[0];
        float acc2 = a2a[0] + a2b[0];
        float tot1 = acc1 + __shfl_xor(acc1, 32, 64);
        float tot2 = acc2 + __shfl_xor(acc2, 32, 64);
        outp[(size_t)j * 128] = half ? tot2 : tot1;   // all 64 lanes store
    }
}

extern "C" void kernel_launch(void* const* d_in, const int* in_sizes, int n_in,
                              void* d_out, int out_size, void* d_ws, size_t ws_size,
                              hipStream_t stream) {
    // inputs: [0]=L (int scalar), [1]=log_dt (H,), [2]=C (H,32,2),
    //         [3]=log_A_real (H,32), [4]=A_imag (H,32)
    const float* log_dt     = (const float*)d_in[1];
    const float* Cv         = (const float*)d_in[2];
    const float* log_A_real = (const float*)d_in[3];
    const float* A_imag     = (const float*)d_in[4];
    float* Kout = (float*)d_out;

    const int Hn = in_sizes[1];          // 1024
    const int L  = out_size / Hn;        // 4096

    dim3 grid(Hn), block(256);
    hipLaunchKernelGGL(s4d_kernel, grid, block, 0, stream,
                       log_dt, Cv, log_A_real, A_imag, Kout, L);
}

// Round 6
// 22.384 us; speedup vs baseline: 4.6089x; 4.6089x over previous
//
#include <hip/hip_runtime.h>
#include <math.h>

#define NH 32      // total modes (N/2)
#define NPAIR 8    // 16 modes per wave, packed 2/v2f
#define MAXSTEPS 16

typedef float v2f __attribute__((ext_vector_type(2)));

// Reduce x mod 2*pi to [-pi, pi] with 2-term float Cody-Waite.
// PI2_HI = 6.28125 (7-bit mantissa) -> k*PI2_HI exact for k < 2^16.
__device__ __forceinline__ float reduce2pi(float x) {
    const float INV2PI = 0.15915494309189535f;
    const float PI2_HI = 6.28125f;
    const float PI2_LO = 1.9353071795864769e-3f;
    float k = rintf(x * INV2PI);
    float r = fmaf(-k, PI2_HI, x);
    r = fmaf(-k, PI2_LO, r);
    return r;
}

// One block per h, 256 threads = 4 waves. Wave w = (cg, mg):
//   mg = w & 1  -> mode group (modes mg*16 .. mg*16+15)
//   cg = w >> 1 -> column group (l-columns cg*64 .. cg*64+63)
// Each lane owns l-column l0 = cg*64 + lane and TWO positions (l0+j*128,
// l0+j*128+L/2), j = 0..15. Modes packed two-per-v2f; recurrence y *= w
// in plain v2f arithmetic (no inline asm - R4/R5's asm+pressure combo
// caused an allocator cliff to VGPR=64 with full-state scratch spill).
// Per step each wave writes ONE v2f partial per lane to a private LDS
// slice; one barrier; phase 2 sums the two mode groups and stores all
// outputs coalesced.
__global__ __launch_bounds__(256, 3) void s4d_kernel(
    const float* __restrict__ log_dt,
    const float* __restrict__ Cv,          // (H, 32, 2)
    const float* __restrict__ log_A_real,  // (H, 32)
    const float* __restrict__ A_imag,      // (H, 32)
    float* __restrict__ Kout,              // (H, L)
    int L)
{
    const int h   = blockIdx.x;
    const int tid = threadIdx.x;
    const int Lh  = L >> 1;                // 2048 (power of 2)
    const int steps = L >> 8;              // 16

    __shared__ float s_cer[NH], s_cei[NH];   // C_eff (x2 folded)
    __shared__ float s_wr [NH], s_wi [NH];   // w = exp(dtA*128)
    __shared__ float s_Br [NH], s_Bi [NH];   // B = exp(dtA*L/2)
    __shared__ float s_dar[NH], s_dai[NH];   // dtA
    __shared__ float s_part[4][MAXSTEPS][64][2];  // [wave][step][lane][pos]

    // ---- Phase A: per-(h,n) uniforms; 32 threads ----
    if (tid < NH) {
        const int n = tid;
        const float dt  = __expf(log_dt[h]);
        const float Ar  = -__expf(log_A_real[h * NH + n]);
        const float Ai  = A_imag[h * NH + n];
        const float dar = Ar * dt;
        const float dai = Ai * dt;

        // C_eff = 2 * C * (exp(dtA) - 1) / A
        float er = __expf(dar);
        float sn, cs;
        __sincosf(dai, &sn, &cs);              // |dai| <= ~9.8
        float edr = fmaf(er, cs, -1.0f);
        float edi = er * sn;
        float inv = 1.0f / fmaf(Ar, Ar, Ai * Ai);
        float fr  = (edr * Ar + edi * Ai) * inv;
        float fi  = (edi * Ar - edr * Ai) * inv;
        float cr  = Cv[(h * NH + n) * 2 + 0];
        float ci  = Cv[(h * NH + n) * 2 + 1];
        s_cer[n] = 2.0f * (cr * fr - ci * fi);
        s_cei[n] = 2.0f * (cr * fi + ci * fr);

        // w = exp(dtA*128); dai*128 exact
        float ew  = __expf(dar * 128.0f);
        float thw = reduce2pi(dai * 128.0f);
        float sw, cw;
        __sincosf(thw, &sw, &cw);
        s_wr[n] = ew * cw;
        s_wi[n] = ew * sw;

        // B = exp(dtA*Lh); dai*Lh exact; may underflow to 0 (mode dead, ok)
        float Bf  = (float)Lh;
        float eB  = __expf(dar * Bf);
        float thB = reduce2pi(dai * Bf);
        float sB, cB;
        __sincosf(thB, &sB, &cB);
        s_Br[n] = eB * cB;
        s_Bi[n] = eB * sB;

        s_dar[n] = dar;
        s_dai[n] = dai;
    }
    __syncthreads();

    const int wave = tid >> 6;
    const int lane = tid & 63;
    const int mg   = wave & 1;             // mode group
    const int cg   = wave >> 1;            // column group
    const int l0   = cg * 64 + lane;       // 0..127
    const float l0f = (float)l0;
    const int n0 = mg * (NH / 2);

    // ---- Phase B: per-thread state init (angles <= ~1240 rad, as R2-R5) ----
    v2f yr0[NPAIR], yi0[NPAIR], yr1[NPAIR], yi1[NPAIR], wr[NPAIR], wi[NPAIR];
    #pragma unroll
    for (int p = 0; p < NPAIR; ++p) {
        #pragma unroll
        for (int q = 0; q < 2; ++q) {
            const int n = n0 + 2 * p + q;
            float e0 = __expf(s_dar[n] * l0f);
            float sn, cs;
            __sincosf(s_dai[n] * l0f, &sn, &cs);
            float zr = e0 * cs, zi = e0 * sn;
            float ar = s_cer[n] * zr - s_cei[n] * zi;
            float ai = s_cer[n] * zi + s_cei[n] * zr;
            yr0[p][q] = ar;
            yi0[p][q] = ai;
            float Br = s_Br[n], Bi = s_Bi[n];
            yr1[p][q] = ar * Br - ai * Bi;   // seed far position (l0 + L/2)
            yi1[p][q] = ar * Bi + ai * Br;
            wr[p][q] = s_wr[n];
            wi[p][q] = s_wi[n];
        }
    }

    // ---- Phase 1: 16 steps; per step one v2f LDS partial per lane ----
    #pragma unroll 2
    for (int j = 0; j < steps; ++j) {
        v2f a0 = {0.f, 0.f}, a1 = {0.f, 0.f};
        #pragma unroll
        for (int p = 0; p < NPAIR; ++p) {
            a0 += yr0[p];
            a1 += yr1[p];
            // complex y *= w (plain v2f math -> VOP3P or scalar pairs)
            v2f t0 = yr0[p] * wr[p] - yi0[p] * wi[p];
            yi0[p] = yr0[p] * wi[p] + yi0[p] * wr[p];
            yr0[p] = t0;
            v2f t1 = yr1[p] * wr[p] - yi1[p] * wi[p];
            yi1[p] = yr1[p] * wi[p] + yi1[p] * wr[p];
            yr1[p] = t1;
        }
        s_part[wave][j][lane][0] = a0[0] + a0[1];
        s_part[wave][j][lane][1] = a1[0] + a1[1];
    }
    __syncthreads();

    // ---- Phase 2: combine mode groups, coalesced stores ----
    const int col = tid & 127;             // output column 0..127
    const int pos = tid >> 7;              // 0: l, 1: l + L/2
    const int cg2 = col >> 6;
    const int ln2 = col & 63;
    float* outp = Kout + (size_t)h * (size_t)L + (size_t)pos * Lh + col;
    #pragma unroll
    for (int j = 0; j < MAXSTEPS; ++j) {
        float v = s_part[2 * cg2 + 0][j][ln2][pos]
                + s_part[2 * cg2 + 1][j][ln2][pos];
        outp[(size_t)j * 128] = v;
    }
}

extern "C" void kernel_launch(void* const* d_in, const int* in_sizes, int n_in,
                              void* d_out, int out_size, void* d_ws, size_t ws_size,
                              hipStream_t stream) {
    // inputs: [0]=L (int scalar), [1]=log_dt (H,), [2]=C (H,32,2),
    //         [3]=log_A_real (H,32), [4]=A_imag (H,32)
    const float* log_dt     = (const float*)d_in[1];
    const float* Cv         = (const float*)d_in[2];
    const float* log_A_real = (const float*)d_in[3];
    const float* A_imag     = (const float*)d_in[4];
    float* Kout = (float*)d_out;

    const int Hn = in_sizes[1];          // 1024
    const int L  = out_size / Hn;        // 4096

    dim3 grid(Hn), block(256);
    hipLaunchKernelGGL(s4d_kernel, grid, block, 0, stream,
                       log_dt, Cv, log_A_real, A_imag, Kout, L);
}

// Round 7
// 11.323 us; speedup vs baseline: 9.1110x; 1.9768x over previous
//
#include <hip/hip_runtime.h>
#include <math.h>

#define NH 32   // modes (N/2)

typedef _Float16 f16;
typedef _Float16 f16x4 __attribute__((ext_vector_type(4)));
typedef float    f32x4 __attribute__((ext_vector_type(4)));

// Reduce x mod 2*pi to [-pi, pi], 2-term float Cody-Waite.
// PI2_HI = 6.28125 (8-bit mantissa) -> k*PI2_HI exact for k < 2^16.
__device__ __forceinline__ float reduce2pi(float x) {
    const float INV2PI = 0.15915494309189535f;
    const float PI2_HI = 6.28125f;
    const float PI2_LO = 1.9353071795864769e-3f;
    float k = rintf(x * INV2PI);
    float r = fmaf(-k, PI2_HI, x);
    r = fmaf(-k, PI2_LO, r);
    return r;
}

// Vandermonde-factored S4D kernel: l = 128a + b  (a<32, b<128)
//   K[h,l] = sum_n Re( G[n,a] * W[n,b] ),  G = c_eff*u^a (u = z^128), W = z^b
// -> per h: one real matmul  K(32a x 128b) = A(32 x 64) * B(64 x 128)
//    A = [Gr | -Gi] (f16, LDS),  B = [Wr ; Wi] (f16, LDS)
// computed with 64x v_mfma_f32_16x16x16f16 per block (16 per wave).
// One block per h, 256 threads = 4 waves; wave wv owns output cols
// [32wv, 32wv+32). ~23 KB LDS, tiny VGPR use.
// Exponentials: phase A computes per-mode z, u=z^128, E1024, E2048 with
// Cody-Waite-reduced EXACT power-of-2 angle scalings; G/W are short fp32
// recurrences (<=15 steps) seeded from angles <= ~1100 rad (the regime
// empirically validated in R2-R6).
__global__ __launch_bounds__(256, 4) void s4d_kernel(
    const float* __restrict__ log_dt,
    const float* __restrict__ Cv,          // (H, 32, 2)
    const float* __restrict__ log_A_real,  // (H, 32)
    const float* __restrict__ A_imag,      // (H, 32)
    float* __restrict__ Kout,              // (H, L), L = 4096
    int L)
{
    const int h   = blockIdx.x;
    const int tid = threadIdx.x;

    // pitch 68 f16 (136 B) pads the 16-row fragment reads from 16-way
    // bank conflict down to ~4-way (negligible at 16 reads/wave).
    __shared__ f16 Alds[32][68];     // A[a][k]: k<32 = Gr[n=k], k>=32 = -Gi
    __shared__ f16 Wlds[128][68];    // B^T[b][k]: k<32 = Wr[n=k], k>=32 = Wi
    __shared__ float s_dar[NH], s_dai[NH];
    __shared__ float s_zr[NH],  s_zi[NH];    // z = exp(dtA)
    __shared__ float s_ur[NH],  s_ui[NH];    // u = z^128
    __shared__ float s_cer[NH], s_cei[NH];   // c_eff (x2 folded)
    __shared__ float s_e1r[NH], s_e1i[NH];   // z^1024
    __shared__ float s_e2r[NH], s_e2i[NH];   // z^2048

    // ---- Phase A: per-mode constants (32 threads) ----
    if (tid < NH) {
        const int n = tid;
        const float dt  = __expf(log_dt[h]);
        const float Ar  = -__expf(log_A_real[h * NH + n]);
        const float Ai  = A_imag[h * NH + n];
        const float dar = Ar * dt;
        const float dai = Ai * dt;

        float er = __expf(dar);
        float sn, cs;
        __sincosf(dai, &sn, &cs);             // |dai| <= ~9.8
        float zr = er * cs, zi = er * sn;     // z = exp(dtA)
        // c_eff = 2 * C * (exp(dtA)-1)/A
        float edr = zr - 1.0f, edi = zi;
        float inv = 1.0f / fmaf(Ar, Ar, Ai * Ai);
        float fr  = (edr * Ar + edi * Ai) * inv;
        float fi  = (edi * Ar - edr * Ai) * inv;
        float cr  = Cv[(h * NH + n) * 2 + 0];
        float ci  = Cv[(h * NH + n) * 2 + 1];
        s_cer[n] = 2.0f * (cr * fr - ci * fi);
        s_cei[n] = 2.0f * (cr * fi + ci * fr);
        s_zr[n] = zr;  s_zi[n] = zi;

        // exact power-of-2 angle scalings + Cody-Waite; exp may underflow
        // to 0 for far blocks (mode fully decayed) - harmless.
        float eu = __expf(dar * 128.0f);
        float su, cu; __sincosf(reduce2pi(dai * 128.0f), &su, &cu);
        s_ur[n] = eu * cu;  s_ui[n] = eu * su;

        float e1 = __expf(dar * 1024.0f);
        float s1, c1; __sincosf(reduce2pi(dai * 1024.0f), &s1, &c1);
        s_e1r[n] = e1 * c1;  s_e1i[n] = e1 * s1;

        float e2 = __expf(dar * 2048.0f);
        float s2, c2; __sincosf(reduce2pi(dai * 2048.0f), &s2, &c2);
        s_e2r[n] = e2 * c2;  s_e2i[n] = e2 * s2;

        s_dar[n] = dar;  s_dai[n] = dai;
    }
    __syncthreads();

    const int lane = tid & 63;
    const int wv   = tid >> 6;       // wave id 0..3

    // ---- G build: wave wv fills A rows a = 8wv..8wv+7 (lanes 0..31) ----
    if (lane < NH) {
        const int n = lane;
        float sr, si;                // seed = z^(1024*wv), exact combos
        if      (wv == 0) { sr = 1.0f;      si = 0.0f; }
        else if (wv == 1) { sr = s_e1r[n];  si = s_e1i[n]; }
        else if (wv == 2) { sr = s_e2r[n];  si = s_e2i[n]; }
        else {
            sr = s_e2r[n] * s_e1r[n] - s_e2i[n] * s_e1i[n];
            si = s_e2r[n] * s_e1i[n] + s_e2i[n] * s_e1r[n];
        }
        float gr = s_cer[n] * sr - s_cei[n] * si;
        float gi = s_cer[n] * si + s_cei[n] * sr;
        const float ur = s_ur[n], ui = s_ui[n];
        #pragma unroll
        for (int s = 0; s < 8; ++s) {
            const int a = wv * 8 + s;
            Alds[a][n]      = (f16)gr;
            Alds[a][n + 32] = (f16)(-gi);
            float t = gr * ur - gi * ui;     // g *= u
            gi = gr * ui + gi * ur;
            gr = t;
        }
    }

    // ---- W build: all 256 threads; thread = (mode n, 16 consecutive b) ----
    {
        const int n  = tid & 31;
        const int bg = tid >> 5;                 // 0..7
        const float b0f = (float)(bg * 16);
        float e0 = __expf(s_dar[n] * b0f);
        float sn, cs;
        __sincosf(s_dai[n] * b0f, &sn, &cs);     // |ang| <= ~1100 rad
        float wr = e0 * cs, wi = e0 * sn;        // W(n, b0)
        const float zr = s_zr[n], zi = s_zi[n];
        #pragma unroll
        for (int i = 0; i < 16; ++i) {
            const int b = bg * 16 + i;
            Wlds[b][n]      = (f16)wr;
            Wlds[b][n + 32] = (f16)wi;
            float t = wr * zr - wi * zi;         // w *= z
            wi = wr * zi + wi * zr;
            wr = t;
        }
    }
    __syncthreads();

    // ---- MFMA: wave wv -> cols [32wv, 32wv+32); 16x mfma 16x16x16 f16 ----
    // A frag: lane l holds A[m = 16mi + (l&15)][k = 16ks + 4(l>>4) + j]
    // B frag: lane l holds B[k = 16ks + 4(l>>4) + j][bcol = 32wv+16ni+(l&15)]
    // D:      lane l holds D[a = 16mi + 4(l>>4) + reg][bcol]
    const int r = lane & 15;
    const int q = lane >> 4;
    float* outp = Kout + (size_t)h * (size_t)L;
    #pragma unroll
    for (int mi = 0; mi < 2; ++mi) {
        #pragma unroll
        for (int ni = 0; ni < 2; ++ni) {
            f32x4 acc = {0.f, 0.f, 0.f, 0.f};
            #pragma unroll
            for (int ks = 0; ks < 4; ++ks) {
                f16x4 af = *(const f16x4*)&Alds[16 * mi + r][16 * ks + 4 * q];
                f16x4 bf = *(const f16x4*)&Wlds[32 * wv + 16 * ni + r][16 * ks + 4 * q];
                acc = __builtin_amdgcn_mfma_f32_16x16x16f16(af, bf, acc, 0, 0, 0);
            }
            const int bcol = 32 * wv + 16 * ni + r;
            #pragma unroll
            for (int reg = 0; reg < 4; ++reg) {
                const int a = 16 * mi + 4 * q + reg;
                outp[a * 128 + bcol] = acc[reg];
            }
        }
    }
}

extern "C" void kernel_launch(void* const* d_in, const int* in_sizes, int n_in,
                              void* d_out, int out_size, void* d_ws, size_t ws_size,
                              hipStream_t stream) {
    // inputs: [0]=L (int scalar), [1]=log_dt (H,), [2]=C (H,32,2),
    //         [3]=log_A_real (H,32), [4]=A_imag (H,32)
    const float* log_dt     = (const float*)d_in[1];
    const float* Cv         = (const float*)d_in[2];
    const float* log_A_real = (const float*)d_in[3];
    const float* A_imag     = (const float*)d_in[4];
    float* Kout = (float*)d_out;

    const int Hn = in_sizes[1];          // 1024
    const int L  = out_size / Hn;        // 4096 (tiling assumes this)

    dim3 grid(Hn), block(256);
    hipLaunchKernelGGL(s4d_kernel, grid, block, 0, stream,
                       log_dt, Cv, log_A_real, A_imag, Kout, L);
}